// Round 1
// 42.937 us; speedup vs baseline: 1.2234x; 1.2234x over previous
//
#include <hip/hip_runtime.h>

// Chamfer distance, N=4, P1=P2=8192, D=3, fp32.
// Round 7: move d^2 to the matrix pipe. v_mfma_f32_32x32x16_bf16 with a
// 2-term bf16 (Ozaki) split computes fp32-accurate partial d^2 tiles:
//   K-slots 0-11: (-2t)_hi/lo x q_hi/lo  (all 4 cross terms -> products exact
//                 in the fp32 accumulator)
//   K-slots 12-14: 3-term bf16 split of ||t||^2 against 1.0
//   ||q||^2 added exactly in fp32 after the chunk-min (per-lane scalar).
// D layout: col = lane&31 (HW-verified) -> per-lane fold of 16 rows via
// 8x v_min3_f32; row mapping is irrelevant (min over all rows). Any
// consistent k-permutation cancels between A and B since both are packed
// by us with the same placement.
// Per wave: RN=4 query tiles (B-frags in regs), sweep 2048-target chunk
// with double-buffered A loads. 524288 MFMAs total -> ~6.9us MFMA floor.

typedef unsigned short u16;
typedef short bf16x8 __attribute__((ext_vector_type(8)));   // 8 bf16 = 4 VGPR
typedef float f32x16 __attribute__((ext_vector_type(16)));  // 16 f32 acc

constexpr int BLK = 256;   // 4 waves
constexpr int TC  = 4;     // target chunks per direction

__device__ __forceinline__ u16 f2bf(float f) {
    unsigned u = __float_as_uint(f);
    return (u16)((u + 0x7FFFu + ((u >> 16) & 1u)) >> 16);   // round-nearest-even
}
__device__ __forceinline__ float bf2f(u16 h) {
    return __uint_as_float((unsigned)h << 16);
}

// Pack per-point MFMA operand vectors (A-role: target, B-role: query),
// store fp32 ||p||^2, init wmin to +inf bits and zero out[].
__global__ void preprocess_kernel(const float* __restrict__ X,
                                  const float* __restrict__ Y,
                                  u16* __restrict__ AX, u16* __restrict__ BX,
                                  u16* __restrict__ AY, u16* __restrict__ BY,
                                  float* __restrict__ QSQ,
                                  unsigned int* __restrict__ wmin,
                                  float* __restrict__ out,
                                  int P1, int P2, int N)
{
    const int t = blockIdx.x * blockDim.x + threadIdx.x;
    const int nx = N * P1;
    const int total = nx + N * P2;
    if (t < total) {
        const bool isX = t < nx;
        const int idx = isX ? t : t - nx;           // n*P + p
        const float* p = (isX ? X : Y) + 3L * idx;
        float c[3] = {p[0], p[1], p[2]};
        float tsq = fmaf(c[0], c[0], fmaf(c[1], c[1], c[2] * c[2]));
        u16 uh[3], ul[3], qh[3], ql[3];
        #pragma unroll
        for (int i = 0; i < 3; ++i) {
            float u = -2.f * c[i];                  // exact
            uh[i] = f2bf(u);    ul[i] = f2bf(u - bf2f(uh[i]));
            qh[i] = f2bf(c[i]); ql[i] = f2bf(c[i] - bf2f(qh[i]));
        }
        u16 s1 = f2bf(tsq);
        float r = tsq - bf2f(s1);
        u16 s2 = f2bf(r);
        u16 s3 = f2bf(r - bf2f(s2));
        const u16 ONE = 0x3F80;                     // bf16 1.0
        alignas(16) u16 av[16] = {uh[0],uh[1],uh[2], uh[0],uh[1],uh[2],
                                  ul[0],ul[1],ul[2], ul[0],ul[1],ul[2],
                                  s1, s2, s3, 0};
        alignas(16) u16 bv[16] = {qh[0],qh[1],qh[2], ql[0],ql[1],ql[2],
                                  qh[0],qh[1],qh[2], ql[0],ql[1],ql[2],
                                  ONE, ONE, ONE, 0};
        u16* ad = (isX ? AX : AY) + (size_t)idx * 16;
        u16* bd = (isX ? BX : BY) + (size_t)idx * 16;
        ((uint4*)ad)[0] = ((const uint4*)av)[0];
        ((uint4*)ad)[1] = ((const uint4*)av)[1];
        ((uint4*)bd)[0] = ((const uint4*)bv)[0];
        ((uint4*)bd)[1] = ((const uint4*)bv)[1];
        QSQ[t]  = tsq;
        wmin[t] = 0xFFFFFFFFu;
    }
    if (t < N) out[t] = 0.f;
}

__global__ __launch_bounds__(BLK) void chamfer_mfma_kernel(
    const u16* __restrict__ AX, const u16* __restrict__ BX,
    const u16* __restrict__ AY, const u16* __restrict__ BY,
    const float* __restrict__ QSQ, unsigned int* __restrict__ wmin,
    int P1, int P2, int N)
{
    const int n    = blockIdx.y;
    const int dir  = blockIdx.z >> 2;   // 0: queries=X, targets=Y ; 1: reverse
    const int chk  = blockIdx.z & 3;
    const int wave = threadIdx.x >> 6;
    const int lane = threadIdx.x & 63;
    const int col  = lane & 31;
    const int half = lane >> 5;

    const int Pq = dir ? P2 : P1;
    const int Pt = dir ? P1 : P2;
    const u16* Bq = (dir ? BY : BX) + (size_t)n * Pq * 16;  // query frags
    const u16* At = (dir ? AX : AY) + (size_t)n * Pt * 16;  // target frags
    const float*  qs = QSQ  + (dir ? (size_t)N * P1 : 0) + (size_t)n * Pq;
    unsigned int* wb = wmin + (dir ? (size_t)N * P1 : 0) + (size_t)n * Pq;

    // ---- 4 query tiles (128 queries) resident per wave ----
    const int qg = blockIdx.x * (BLK / 64) + wave;   // 0..63
    const int q0 = qg * 128 + col;
    const bf16x8 b0 = *(const bf16x8*)(Bq + (size_t)(q0      ) * 16 + half * 8);
    const bf16x8 b1 = *(const bf16x8*)(Bq + (size_t)(q0 +  32) * 16 + half * 8);
    const bf16x8 b2 = *(const bf16x8*)(Bq + (size_t)(q0 +  64) * 16 + half * 8);
    const bf16x8 b3 = *(const bf16x8*)(Bq + (size_t)(q0 +  96) * 16 + half * 8);
    const float qs0 = qs[q0], qs1 = qs[q0 + 32], qs2 = qs[q0 + 64], qs3 = qs[q0 + 96];
    float m0 = 1e30f, m1 = 1e30f, m2 = 1e30f, m3 = 1e30f;

    f32x16 zc;
    #pragma unroll
    for (int i = 0; i < 16; ++i) zc[i] = 0.f;

    #define MFMA(A, B) __builtin_amdgcn_mfma_f32_32x32x16_bf16((A), (B), zc, 0, 0, 0)

    auto fold = [&](const f32x16& d, float& mm) {
        #pragma unroll
        for (int i = 0; i < 16; i += 2) {
            float x0 = d[i], x1 = d[i + 1];
            asm("v_min3_f32 %0, %1, %2, %0" : "+v"(mm) : "v"(x0), "v"(x1));
        }
    };

    // ---- sweep the target chunk: 64 tiles of 32 points, dbuf A loads ----
    const int tpc = Pt >> 2;                 // 2048 targets per chunk
    const int NT  = tpc >> 5;                // 64 tiles
    const u16* ap = At + ((size_t)(chk * tpc + col)) * 16 + half * 8;

    bf16x8 a0 = *(const bf16x8*)(ap);
    bf16x8 a1 = *(const bf16x8*)(ap + 512);
    #pragma unroll 1
    for (int g = 0; g < NT; g += 2) {
        f32x16 d0 = MFMA(a0, b0), d1 = MFMA(a0, b1),
               d2 = MFMA(a0, b2), d3 = MFMA(a0, b3);
        a0 = *(const bf16x8*)(ap + (size_t)min(g + 2, NT - 1) * 512);
        fold(d0, m0); fold(d1, m1); fold(d2, m2); fold(d3, m3);
        f32x16 e0 = MFMA(a1, b0), e1 = MFMA(a1, b1),
               e2 = MFMA(a1, b2), e3 = MFMA(a1, b3);
        a1 = *(const bf16x8*)(ap + (size_t)min(g + 3, NT - 1) * 512);
        fold(e0, m0); fold(e1, m1); fold(e2, m2); fold(e3, m3);
    }
    #undef MFMA

    // ---- combine across chunks: uint atomicMin on clamped d^2 ----
    // Both lane halves hold partial mins over disjoint target rows for the
    // same query column -> both atomic (2-way same-address, harmless).
    float v0 = fmaxf(m0 + qs0, 0.f);
    float v1 = fmaxf(m1 + qs1, 0.f);
    float v2 = fmaxf(m2 + qs2, 0.f);
    float v3 = fmaxf(m3 + qs3, 0.f);
    atomicMin(&wb[q0      ], __float_as_uint(v0));
    atomicMin(&wb[q0 +  32], __float_as_uint(v1));
    atomicMin(&wb[q0 +  64], __float_as_uint(v2));
    atomicMin(&wb[q0 +  96], __float_as_uint(v3));
}

// 64 blocks: sqrt + scaled partial sums, one atomicAdd per block.
__global__ __launch_bounds__(BLK) void chamfer_reduce_kernel(
    const unsigned int* __restrict__ wmin, float* __restrict__ out,
    int P1, int P2, int N)
{
    __shared__ float wsum[BLK / 64];
    const int dir = blockIdx.z;
    const int n   = blockIdx.y;
    const int Pa  = dir ? P2 : P1;
    const unsigned int* base = wmin + (dir ? (long)N * P1 : 0) + (long)n * Pa;

    float s = 0.f;
    for (int i = blockIdx.x * BLK + threadIdx.x; i < Pa; i += gridDim.x * BLK)
        s += sqrtf(__uint_as_float(base[i]));

    for (int off = 32; off > 0; off >>= 1)
        s += __shfl_down(s, off);
    const int lane = threadIdx.x & 63, wid = threadIdx.x >> 6;
    if (lane == 0) wsum[wid] = s;
    __syncthreads();
    if (threadIdx.x == 0) {
        float t = 0.f;
        #pragma unroll
        for (int w = 0; w < BLK / 64; ++w) t += wsum[w];
        atomicAdd(&out[n], t / (float)Pa);
    }
}

extern "C" void kernel_launch(void* const* d_in, const int* in_sizes, int n_in,
                              void* d_out, int out_size, void* d_ws, size_t ws_size,
                              hipStream_t stream)
{
    const float* x = (const float*)d_in[0];
    const float* y = (const float*)d_in[1];
    float* out = (float*)d_out;

    const int N  = out_size;                 // 4
    const int P1 = in_sizes[0] / (N * 3);    // 8192
    const int P2 = in_sizes[1] / (N * 3);    // 8192

    // ws layout: AX|BX [N*P1*16 u16 each], AY|BY [N*P2*16 u16 each],
    //            QSQ [N*(P1+P2)] f32, wmin [N*(P1+P2)] u32.  ~4.5 MB total.
    u16* AX = (u16*)d_ws;
    u16* BX = AX + (size_t)N * P1 * 16;
    u16* AY = BX + (size_t)N * P1 * 16;
    u16* BY = AY + (size_t)N * P2 * 16;
    float* QSQ = (float*)(BY + (size_t)N * P2 * 16);
    unsigned int* wmin = (unsigned int*)(QSQ + (size_t)N * (P1 + P2));

    const int total = N * (P1 + P2);
    preprocess_kernel<<<(total + BLK - 1) / BLK, BLK, 0, stream>>>(
        x, y, AX, BX, AY, BY, QSQ, wmin, out, P1, P2, N);

    // grid: x = query-groups/4 waves, y = n, z = dir*TC + chunk
    const int gx = (P1 / 128) / (BLK / 64);  // 16
    chamfer_mfma_kernel<<<dim3(gx, N, 2 * TC), BLK, 0, stream>>>(
        AX, BX, AY, BY, QSQ, wmin, P1, P2, N);

    chamfer_reduce_kernel<<<dim3(8, N, 2), BLK, 0, stream>>>(wmin, out, P1, P2, N);
}